// Round 1
// baseline (80.066 us; speedup 1.0000x reference)
//
#include <hip/hip_runtime.h>

typedef unsigned short u16;
typedef unsigned int u32;
typedef __attribute__((ext_vector_type(8))) short bfx8;
typedef __attribute__((ext_vector_type(4))) float fx4;
typedef __attribute__((ext_vector_type(4))) u32 ux4;
typedef __attribute__((ext_vector_type(2))) u32 ux2;

#define KELEMS (64 * 32 * 256) /* 524288 kernel elements */
#define XELEMS (16 * 32 * 256) /* 131072 x elements */
#define WS1_OFFB (KELEMS * 2)            /* x_bf16 at byte 1048576 */
#define WS2_OFFB (WS1_OFFB + XELEMS * 2) /* partials at byte 1310720 */

__device__ inline u16 f2bf(float v) {
  u32 u = __builtin_bit_cast(u32, v);
  u = (u + 0x7fffu + ((u >> 16) & 1u)) >> 16; // RNE
  return (u16)u;
}

// ---------------- fp32 -> bf16 converter; kernel relaid to [i][f][s] ----------------
__global__ __launch_bounds__(256) void eq_convert(const float* __restrict__ kin,
                                                  const float* __restrict__ xin,
                                                  u16* __restrict__ kbf,
                                                  u16* __restrict__ xbf) {
  int e = (blockIdx.x * 256 + threadIdx.x) * 4;
  if (e < KELEMS) {
    fx4 v = *(const fx4*)(kin + e);          // input layout [f][i][s]
    int f = e >> 13, i = (e >> 8) & 31, s = e & 255;
    int o = ((i << 6) + f) * 256 + s;        // output layout [i][f][s]
    ux2 p;
    p[0] = (u32)f2bf(v[0]) | ((u32)f2bf(v[1]) << 16);
    p[1] = (u32)f2bf(v[2]) | ((u32)f2bf(v[3]) << 16);
    *(ux2*)(kbf + o) = p;
  } else {
    int ex = e - KELEMS;                     // x: straight copy [b][i][s]
    fx4 v = *(const fx4*)(xin + ex);
    ux2 p;
    p[0] = (u32)f2bf(v[0]) | ((u32)f2bf(v[1]) << 16);
    p[1] = (u32)f2bf(v[2]) | ((u32)f2bf(v[3]) << 16);
    *(ux2*)(xbf + ex) = p;
  }
}

// ---------------- main MFMA kernel ----------------
// Grid: 512 blocks = 16 b * 32 i-chunks (1 i each). Block: 256 thr = 4 waves.
// Wave w computes out-tile [64 f][h in w*64..w*64+64) for one (b, i) partial.
__global__ __launch_bounds__(256, 2) void eq_main(const u16* __restrict__ kbf,
                                                  const u16* __restrict__ xbf,
                                                  float* __restrict__ part) {
  __shared__ u16 As[16384];  // kernel slice [64 f][256 s], 16B chunks XOR-swizzled
  __shared__ u16 xraw[256];  // x[b][i][0..255]
  __shared__ u32 P[512];     // pre-rotated paired dwords: [16 r][par 0/1][16 u]

  const int bid = blockIdx.x;
  const int b = bid & 15;
  const int i = bid >> 4;
  const int t = threadIdx.x;

  // Stage A: swizzle chunk' = chunk ^ (f&31) so ds_read_b128 is conflict-free.
  const u16* ks = kbf + i * 16384;
#pragma unroll
  for (int it = 0; it < 8; ++it) {
    int slot = it * 256 + t;             // 16B-chunk slot 0..2047
    int f = slot >> 5;
    int c = (slot & 31) ^ (f & 31);      // source chunk within f's row
    ux4 v = *(const ux4*)(ks + f * 256 + c * 8);
    *(ux4*)(As + slot * 8) = v;
  }
  if (t < 64) {
    ux2 v = *(const ux2*)(xbf + ((b << 5) + i) * 256 + t * 4);
    *(ux2*)(xraw + t * 4) = v;
  }
  __syncthreads();

  // Build P: P_e[r][u] = pack(row[(-2u)&15], row[(-2u-1)&15])
  //          P_o[r][u] = pack(row[(-2u-1)&15], row[(-2u-2)&15])
  {
    int r = t >> 4, u = t & 15;
    int c0 = (32 - 2 * u) & 15;
    int c1 = (c0 + 15) & 15;
    int c2 = (c0 + 14) & 15;
    u32 va = xraw[r * 16 + c0];
    u32 vb = xraw[r * 16 + c1];
    u32 vc = xraw[r * 16 + c2];
    P[r * 32 + u] = va | (vb << 16);
    P[r * 32 + 16 + u] = vb | (vc << 16);
  }
  __syncthreads();

  const int lane = t & 63;
  const int w = t >> 6;
  const int n = lane & 15;        // MFMA col (h low bits) / A row (f low bits)
  const int quad = lane >> 4;     // k-group
  const int s2_0 = (quad & 1) << 3;
  const int par = n & 1;
  const int u0 = ((s2_0 - n - par) & 15) >> 1;
  const int Pb = (par << 4) + u0; // lane's base dword within a P row
  const int s1q = quad >> 1;

  fx4 acc[4][4];
#pragma unroll
  for (int a = 0; a < 4; ++a)
#pragma unroll
    for (int c = 0; c < 4; ++c) acc[a][c] = (fx4){0.f, 0.f, 0.f, 0.f};

#pragma unroll
  for (int kstep = 0; kstep < 8; ++kstep) {
    bfx8 af[4];
#pragma unroll
    for (int ft = 0; ft < 4; ++ft) {
      int f = (ft << 4) + n;                          // A: m = lane&15
      int ch = ((kstep << 2) + quad) ^ (f & 31);      // un-swizzle
      af[ft] = *(const bfx8*)(As + f * 256 + ch * 8); // k = quad*8 + j
    }
    const int s1 = (kstep << 1) + s1q;
    bfx8 bfr[4];
#pragma unroll
    for (int ht = 0; ht < 4; ++ht) {
      int r = ((w << 2) + ht - s1) & 15;              // x row (h1 - s1) mod 16
      int idx = r * 32 + Pb;
      ux4 bv = {P[idx], P[idx + 1], P[idx + 2], P[idx + 3]};
      bfr[ht] = __builtin_bit_cast(bfx8, bv);         // B[k][n], rotated row
    }
#pragma unroll
    for (int ft = 0; ft < 4; ++ft)
#pragma unroll
      for (int ht = 0; ht < 4; ++ht)
        acc[ft][ht] =
            __builtin_amdgcn_mfma_f32_16x16x32_bf16(af[ft], bfr[ht], acc[ft][ht], 0, 0, 0);
  }

  // Epilogue: D row = quad*4 + reg (f), col = n (h). Partial per (i, b).
  float* pw = part + (((i << 4) + b) << 14);
#pragma unroll
  for (int ft = 0; ft < 4; ++ft) {
#pragma unroll
    for (int reg = 0; reg < 4; ++reg) {
      int f = (ft << 4) + (quad << 2) + reg;
#pragma unroll
      for (int ht = 0; ht < 4; ++ht) {
        int h = (w << 6) + (ht << 4) + n;
        pw[f * 256 + h] = acc[ft][ht][reg];
      }
    }
  }
}

// ---------------- split-K reduction + bias ----------------
__global__ __launch_bounds__(256) void eq_reduce(const float* __restrict__ part,
                                                 const float* __restrict__ bias,
                                                 float* __restrict__ out) {
  int o = (blockIdx.x * 256 + threadIdx.x) * 4;
  fx4 s = {0.f, 0.f, 0.f, 0.f};
#pragma unroll
  for (int i = 0; i < 32; ++i) s = s + *(const fx4*)(part + i * 262144 + o);
  float bv = bias[(o >> 8) & 63];
  s = s + (fx4){bv, bv, bv, bv};
  *(fx4*)(out + o) = s;
}

extern "C" void kernel_launch(void* const* d_in, const int* in_sizes, int n_in,
                              void* d_out, int out_size, void* d_ws, size_t ws_size,
                              hipStream_t stream) {
  (void)in_sizes; (void)n_in; (void)out_size; (void)ws_size;
  const float* x = (const float*)d_in[0];
  const float* k = (const float*)d_in[1];
  const float* bias = (const float*)d_in[2];
  // d_in[3] (product_table) not needed: translation group indices are computed analytically.
  u16* kbf = (u16*)((char*)d_ws);
  u16* xbf = (u16*)((char*)d_ws + WS1_OFFB);
  float* part = (float*)((char*)d_ws + WS2_OFFB);
  float* out = (float*)d_out;

  eq_convert<<<640, 256, 0, stream>>>(k, x, kbf, xbf);
  eq_main<<<512, 256, 0, stream>>>(kbf, xbf, part);
  eq_reduce<<<256, 256, 0, stream>>>(part, bias, out);
}

// Round 2
// 73.456 us; speedup vs baseline: 1.0900x; 1.0900x over previous
//
#include <hip/hip_runtime.h>

typedef unsigned short u16;
typedef unsigned int u32;
typedef __attribute__((ext_vector_type(8))) short bfx8;
typedef __attribute__((ext_vector_type(4))) float fx4;
typedef __attribute__((ext_vector_type(4))) u32 ux4;
typedef __attribute__((ext_vector_type(2))) u32 ux2;

__device__ inline u32 f2bf(float v) {
  u32 u = __builtin_bit_cast(u32, v);
  u = (u + 0x7fffu + ((u >> 16) & 1u)) >> 16; // RNE
  return u;
}

// ---------------- main MFMA kernel (conversion fused, split-K=16) ----------------
// Grid: 256 blocks = 16 b * 16 ichunk (2 i each). Block: 512 thr = 8 waves.
// Wave w: i = ich*2 + (w>>2), h-quarter wq = w&3 -> [64 f][64 h] tile, 8 ksteps.
// Epilogue: waves 4..7 (i odd) dump acc to LDS; waves 0..3 add -> one partial
// per (ich, b): part[(ich*16+b)*16384 + f*256 + h], 16 chunks total (16.8 MB).
__global__ __launch_bounds__(512, 1) void eq_main(const float* __restrict__ xin,
                                                  const float* __restrict__ kin,
                                                  float* __restrict__ part) {
  __shared__ u16 As[32768];        // [2 i][64 f][256 s] bf16, 16B chunks XOR-swizzled
  __shared__ u32 P[1024];          // [2 i][16 r][2 par][16 u] pre-rotated pairs
  __shared__ u16 xraw[512];        // [2 i][256 s] bf16 bits
  __shared__ float red[4 * 64 * 68]; // [wq][hlocal][f pad 68] cross-wave reduce buf

  const int b = blockIdx.x & 15;
  const int ich = blockIdx.x >> 4;
  const int t = threadIdx.x;

  // ---- stage x (2 rows of 256 fp32 -> bf16) ----
  if (t < 128) {
    int iLoc = t >> 6, s4 = (t & 63) << 2;
    fx4 v = *(const fx4*)(xin + ((b << 5) + (ich << 1) + iLoc) * 256 + s4);
    ux2 p;
    p[0] = f2bf(v[0]) | (f2bf(v[1]) << 16);
    p[1] = f2bf(v[2]) | (f2bf(v[3]) << 16);
    *(ux2*)(xraw + iLoc * 256 + s4) = p;
  }

  // ---- stage kernel slice: 2 i * 64 f * 256 s fp32 -> bf16 LDS, swizzled ----
  // slot = 16B chunk id; swizzle chunk' = chunk ^ (f&31) for conflict-free b128 reads.
#pragma unroll
  for (int it = 0; it < 8; ++it) {
    int slot = it * 512 + t;            // 0..4095
    int iLoc = slot >> 11;
    int f = (slot >> 5) & 63;
    int c = slot & 31;
    int cs = c ^ (f & 31);
    const float* src = kin + f * 8192 + ((ich << 1) + iLoc) * 256 + (cs << 3);
    fx4 v0 = *(const fx4*)src;
    fx4 v1 = *(const fx4*)(src + 4);
    ux4 p;
    p[0] = f2bf(v0[0]) | (f2bf(v0[1]) << 16);
    p[1] = f2bf(v0[2]) | (f2bf(v0[3]) << 16);
    p[2] = f2bf(v1[0]) | (f2bf(v1[1]) << 16);
    p[3] = f2bf(v1[2]) | (f2bf(v1[3]) << 16);
    *(ux4*)(As + slot * 8) = p;
  }
  __syncthreads();

  // ---- build P: pre-rotated paired dwords per i ----
  {
    int iLoc = t >> 8, tt = t & 255;
    int r = tt >> 4, u = tt & 15;
    int c0 = (32 - 2 * u) & 15;
    int c1 = (c0 + 15) & 15;
    int c2 = (c0 + 14) & 15;
    const u16* xr = xraw + iLoc * 256 + r * 16;
    u32 va = xr[c0], vb = xr[c1], vc = xr[c2];
    P[iLoc * 512 + r * 32 + u] = va | (vb << 16);
    P[iLoc * 512 + r * 32 + 16 + u] = vb | (vc << 16);
  }
  __syncthreads();

  const int lane = t & 63;
  const int w = t >> 6;
  const int iLoc = w >> 2;
  const int wq = w & 3;
  const int n = lane & 15;
  const int quad = lane >> 4;
  const int s2_0 = (quad & 1) << 3;
  const int par = n & 1;
  const int u0 = ((s2_0 - n - par) & 15) >> 1;
  const int Pb = iLoc * 512 + (par << 4) + u0;
  const int s1q = quad >> 1;
  const u16* Aw = As + (iLoc << 14);

  fx4 acc[4][4];
#pragma unroll
  for (int a = 0; a < 4; ++a)
#pragma unroll
    for (int c = 0; c < 4; ++c) acc[a][c] = (fx4){0.f, 0.f, 0.f, 0.f};

#pragma unroll
  for (int kstep = 0; kstep < 8; ++kstep) {
    bfx8 af[4];
#pragma unroll
    for (int ft = 0; ft < 4; ++ft) {
      int f = (ft << 4) + n;
      int ch = ((kstep << 2) + quad) ^ (f & 31);
      af[ft] = *(const bfx8*)(Aw + f * 256 + ch * 8);
    }
    const int s1 = (kstep << 1) + s1q;
    bfx8 bfr[4];
#pragma unroll
    for (int ht = 0; ht < 4; ++ht) {
      int r = ((wq << 2) + ht - s1) & 15;
      int idx = r * 32 + Pb;
      ux4 bv = {P[idx], P[idx + 1], P[idx + 2], P[idx + 3]};
      bfr[ht] = __builtin_bit_cast(bfx8, bv);
    }
#pragma unroll
    for (int ft = 0; ft < 4; ++ft)
#pragma unroll
      for (int ht = 0; ht < 4; ++ht)
        acc[ft][ht] =
            __builtin_amdgcn_mfma_f32_16x16x32_bf16(af[ft], bfr[ht], acc[ft][ht], 0, 0, 0);
  }

  // ---- cross-wave (i) reduction: upper waves write, lower add + store ----
  if (w >= 4) {
#pragma unroll
    for (int ft = 0; ft < 4; ++ft)
#pragma unroll
      for (int ht = 0; ht < 4; ++ht) {
        float* pr = &red[wq * 4352 + (ht * 16 + n) * 68 + (ft << 4) + (quad << 2)];
        *(fx4*)pr = acc[ft][ht];
      }
  }
  __syncthreads();
  if (w < 4) {
    float* pw = part + (((ich << 4) + b) << 14);
#pragma unroll
    for (int ft = 0; ft < 4; ++ft)
#pragma unroll
      for (int ht = 0; ht < 4; ++ht) {
        const float* pr = &red[wq * 4352 + (ht * 16 + n) * 68 + (ft << 4) + (quad << 2)];
        fx4 vv = *(const fx4*)pr;
        acc[ft][ht] = acc[ft][ht] + vv;
#pragma unroll
        for (int reg = 0; reg < 4; ++reg) {
          int f = (ft << 4) + (quad << 2) + reg;
          int h = (wq << 6) + (ht << 4) + n;
          pw[f * 256 + h] = acc[ft][ht][reg];
        }
      }
  }
}

// ---------------- split-K reduction + bias ----------------
__global__ __launch_bounds__(256) void eq_reduce(const float* __restrict__ part,
                                                 const float* __restrict__ bias,
                                                 float* __restrict__ out) {
  int o = (blockIdx.x * 256 + threadIdx.x) * 4;
  fx4 s = {0.f, 0.f, 0.f, 0.f};
#pragma unroll
  for (int i = 0; i < 16; ++i) s = s + *(const fx4*)(part + i * 262144 + o);
  float bv = bias[(o >> 8) & 63];
  s = s + (fx4){bv, bv, bv, bv};
  *(fx4*)(out + o) = s;
}

extern "C" void kernel_launch(void* const* d_in, const int* in_sizes, int n_in,
                              void* d_out, int out_size, void* d_ws, size_t ws_size,
                              hipStream_t stream) {
  (void)in_sizes; (void)n_in; (void)out_size; (void)ws_size;
  const float* x = (const float*)d_in[0];
  const float* k = (const float*)d_in[1];
  const float* bias = (const float*)d_in[2];
  // d_in[3] (product_table) unused: translation-group indices computed analytically.
  float* part = (float*)d_ws;   // 16 chunks * 16 b * 64 f * 256 h * 4 B = 16.8 MB
  float* out = (float*)d_out;

  eq_main<<<256, 512, 0, stream>>>(x, k, part);
  eq_reduce<<<256, 256, 0, stream>>>(part, bias, out);
}